// Round 6
// baseline (332.505 us; speedup 1.0000x reference)
//
#include <hip/hip_runtime.h>
#include <hip/hip_bf16.h>

#define TEMP_INV 20.0f
#define BATCH    1024
#define NSAMP    100000
#define NFEAT    256
#define BM       128
#define BN       128
#define BK       64
#define NCH      ((NSAMP + BN - 1) / BN)   /* 782 */
#define NCH_PAD  784                        /* 8 * 98 */

typedef __bf16 bf16x8 __attribute__((ext_vector_type(8)));
typedef float  f32x4  __attribute__((ext_vector_type(4)));
typedef float  f32x4v __attribute__((ext_vector_type(4)));

// async global->LDS, 16B per lane; LDS dest = wave-uniform base + lane*16
#define GLOAD_LDS16(g, l) __builtin_amdgcn_global_load_lds(               \
    (const __attribute__((address_space(1))) void*)(g),                   \
    (__attribute__((address_space(3))) void*)(l), 16, 0, 0)

// ---------------------------------------------------------------------------
// Kernel 1 (fused): bf16 convert of feats (+zero pad) and inputs, rowsum
// zero-init, and per-row target logit + softmax shift.
// Block roles (uniform per block):
//   [0,3125)     feats convert, 4 units (8 elems) per thread, nontemporal
//   [3125,3128)  zero-pad fb rows 100000..100096; block 3125 zeros rowsum
//   [3128,3160)  inputs convert
//   [3160,3416)  target: row = (b-3160)*4 + wave; tlogit + mrow
// mrow = 5.4*||x_row|| (Gumbel-mode shift; exponents stay f32-safe, padded
// zero-rows underflow to 0 -> no masking needed anywhere).
// ---------------------------------------------------------------------------
__global__ __launch_bounds__(256) void convert_target_kernel(
    const float* __restrict__ feats, const float* __restrict__ inputs,
    const int* __restrict__ targets,
    __bf16* __restrict__ fb, __bf16* __restrict__ ib,
    float* __restrict__ tlogit, float* __restrict__ mrow,
    float* __restrict__ rowsum)
{
    int b = blockIdx.x;
    if (b < 3125) {
        size_t u0 = (size_t)b * 1024 + threadIdx.x;
        #pragma unroll
        for (int i = 0; i < 4; i++) {
            size_t u = u0 + (size_t)i * 256;
            const f32x4v* src = (const f32x4v*)(feats + u * 8);
            f32x4v a = __builtin_nontemporal_load(src);
            f32x4v c = __builtin_nontemporal_load(src + 1);
            bf16x8 o;
            o[0] = (__bf16)a[0]; o[1] = (__bf16)a[1]; o[2] = (__bf16)a[2]; o[3] = (__bf16)a[3];
            o[4] = (__bf16)c[0]; o[5] = (__bf16)c[1]; o[6] = (__bf16)c[2]; o[7] = (__bf16)c[3];
            __builtin_nontemporal_store(o, (bf16x8*)(fb + u * 8));
        }
    } else if (b < 3128) {
        size_t u0 = 3200000 + (size_t)(b - 3125) * 1024 + threadIdx.x;
        bf16x8 z;
        #pragma unroll
        for (int q = 0; q < 8; q++) z[q] = (__bf16)0.0f;
        #pragma unroll
        for (int i = 0; i < 4; i++)
            *(bf16x8*)(fb + (u0 + (size_t)i * 256) * 8) = z;
        if (b == 3125) {               // zero the atomic row-sum accumulator
            f32x4 zf = {0.f, 0.f, 0.f, 0.f};
            *(f32x4*)(rowsum + threadIdx.x * 4) = zf;
        }
    } else if (b < 3160) {
        size_t u0 = (size_t)(b - 3128) * 1024 + threadIdx.x;
        #pragma unroll
        for (int i = 0; i < 4; i++) {
            size_t u = u0 + (size_t)i * 256;
            const f32x4v* src = (const f32x4v*)(inputs + u * 8);
            f32x4v a = __builtin_nontemporal_load(src);
            f32x4v c = __builtin_nontemporal_load(src + 1);
            bf16x8 o;
            o[0] = (__bf16)a[0]; o[1] = (__bf16)a[1]; o[2] = (__bf16)a[2]; o[3] = (__bf16)a[3];
            o[4] = (__bf16)c[0]; o[5] = (__bf16)c[1]; o[6] = (__bf16)c[2]; o[7] = (__bf16)c[3];
            __builtin_nontemporal_store(o, (bf16x8*)(ib + u * 8));
        }
    } else {
        int lane = threadIdx.x & 63;
        int wid  = threadIdx.x >> 6;
        int row  = (b - 3160) * 4 + wid;
        int tgt  = targets[row];
        const float4* a = (const float4*)(inputs + (size_t)row * NFEAT);
        const float4* f = (const float4*)(feats  + (size_t)tgt * NFEAT);
        float4 av = a[lane];
        float4 fv = f[lane];
        float d  = av.x * fv.x + av.y * fv.y + av.z * fv.z + av.w * fv.w;
        float n2 = av.x * av.x + av.y * av.y + av.z * av.z + av.w * av.w;
        #pragma unroll
        for (int off = 1; off < 64; off <<= 1) {
            d  += __shfl_xor(d, off, 64);
            n2 += __shfl_xor(n2, off, 64);
        }
        if (lane == 0) {
            tlogit[row] = d * TEMP_INV;
            mrow[row]   = 5.4f * sqrtf(n2);
        }
    }
}

// ---------------------------------------------------------------------------
// Kernel 2: bf16 MFMA GEMM (global_load_lds staging, XOR-swizzled LDS) +
// fixed-shift exp-sum epilogue with DIRECT global atomics into rowsum.
// 128x128 tile, BK=64, 4 waves (2x2 of 64x64). LDS exactly 32 KB.
// ---------------------------------------------------------------------------
__global__ __launch_bounds__(256, 4) void gemm_softmax_kernel(
    const __bf16* __restrict__ A, const __bf16* __restrict__ B,
    const float* __restrict__ mrow, float* __restrict__ rowsum)
{
    int L  = blockIdx.x;
    int j  = L & 7;                 // XCD id (round-robin)
    int t  = L >> 3;
    int mx = t & 7;                 // m-tile sweeps fastest -> B-chunk L2 reuse
    int ny = (t >> 3) * 8 + j;
    if (ny >= NCH) return;
    int m0 = mx * BM;
    int n0 = ny * BN;

    __shared__ __bf16 Alds[BM][BK];
    __shared__ __bf16 Blds[BN][BK];

    int tid  = threadIdx.x;
    int lane = tid & 63;
    int wid  = tid >> 6;
    int wm   = wid & 1;
    int wn   = wid >> 1;
    int lrow = lane & 15;
    int quad = lane >> 4;

    f32x4 acc[4][4] = {};

    int rowoff = lane >> 3;
    int p      = lane & 7;
    int kc     = p ^ rowoff;        // XOR chunk swizzle (0 bank conflicts)
    const __bf16* Ag = A + (size_t)(m0 + wid * 32 + rowoff) * NFEAT + kc * 8;
    const __bf16* Bg = B + (size_t)(n0 + wid * 32 + rowoff) * NFEAT + kc * 8;

    for (int k0 = 0; k0 < NFEAT; k0 += BK) {
        __syncthreads();
        #pragma unroll
        for (int i = 0; i < 4; i++) {
            GLOAD_LDS16(Ag + k0 + i * 8 * NFEAT, &Alds[wid * 32 + i * 8][0]);
            GLOAD_LDS16(Bg + k0 + i * 8 * NFEAT, &Blds[wid * 32 + i * 8][0]);
        }
        __syncthreads();
        #pragma unroll
        for (int ks = 0; ks < 2; ks++) {
            bf16x8 af[4], bfr[4];
            #pragma unroll
            for (int mi = 0; mi < 4; mi++) {
                int R = wm * 64 + mi * 16 + lrow;
                af[mi] = *(bf16x8*)&Alds[R][((ks * 4 + quad) ^ (R & 7)) * 8];
            }
            #pragma unroll
            for (int ni = 0; ni < 4; ni++) {
                int R = wn * 64 + ni * 16 + lrow;
                bfr[ni] = *(bf16x8*)&Blds[R][((ks * 4 + quad) ^ (R & 7)) * 8];
            }
            #pragma unroll
            for (int mi = 0; mi < 4; mi++)
                #pragma unroll
                for (int ni = 0; ni < 4; ni++)
                    acc[mi][ni] = __builtin_amdgcn_mfma_f32_16x16x32_bf16(
                        af[mi], bfr[ni], acc[mi][ni], 0, 0, 0);
        }
    }

    // ---- epilogue: s = sum_cols exp(20*acc - m_row); atomicAdd per row ----
    // C layout: row = quad*4 + reg, col = lane&15 per 16x16 tile
    #pragma unroll
    for (int mi = 0; mi < 4; mi++) {
        #pragma unroll
        for (int reg = 0; reg < 4; reg++) {
            int r = m0 + wm * 64 + mi * 16 + quad * 4 + reg;
            float mrv = mrow[r];
            float s = __expf(acc[mi][0][reg] * TEMP_INV - mrv)
                    + __expf(acc[mi][1][reg] * TEMP_INV - mrv)
                    + __expf(acc[mi][2][reg] * TEMP_INV - mrv)
                    + __expf(acc[mi][3][reg] * TEMP_INV - mrv);
            #pragma unroll
            for (int off = 1; off < 16; off <<= 1)
                s += __shfl_xor(s, off, 64);
            if (lrow == 0)
                atomicAdd(&rowsum[r], s);
        }
    }
}

// ---------------------------------------------------------------------------
// Kernel 3: finalize — nll = mrow + log(rowsum) - tlogit; out = mean.
// One block, 1024 threads (16 waves).
// ---------------------------------------------------------------------------
__global__ __launch_bounds__(1024) void final_kernel(
    const float* __restrict__ rowsum, const float* __restrict__ tlogit,
    const float* __restrict__ mrow, float* __restrict__ out)
{
    __shared__ float wsum[16];
    int tid = threadIdx.x;
    float nll = (mrow[tid] + logf(rowsum[tid])) - tlogit[tid];
    #pragma unroll
    for (int off = 1; off < 64; off <<= 1)
        nll += __shfl_xor(nll, off, 64);
    if ((tid & 63) == 0) wsum[tid >> 6] = nll;
    __syncthreads();
    if (tid == 0) {
        float t = 0.f;
        #pragma unroll
        for (int i = 0; i < 16; i++) t += wsum[i];
        out[0] = t * (1.0f / BATCH);
    }
}

// ---------------------------------------------------------------------------
extern "C" void kernel_launch(void* const* d_in, const int* in_sizes, int n_in,
                              void* d_out, int out_size, void* d_ws, size_t ws_size,
                              hipStream_t stream) {
    const float* inputs  = (const float*)d_in[0];
    const int*   targets = (const int*)d_in[1];
    const float* feats   = (const float*)d_in[2];
    float* out = (float*)d_out;

    // ws layout (bytes):
    //   fb     : 0          .. 51,249,152   (100096*256 bf16)
    //   ib     : 51,249,152 .. 51,773,440   (1024*256 bf16)
    //   tlogit : 51,773,440 .. +4096
    //   mrow   : 51,777,536 .. +4096
    //   rowsum : 51,781,632 .. +4096
    __bf16* fb     = (__bf16*)d_ws;
    __bf16* ib     = (__bf16*)((char*)d_ws + 51249152);
    float*  tlogit = (float*)((char*)d_ws + 51773440);
    float*  mrow   = (float*)((char*)d_ws + 51777536);
    float*  rowsum = (float*)((char*)d_ws + 51781632);

    convert_target_kernel<<<3416, 256, 0, stream>>>(
        feats, inputs, targets, fb, ib, tlogit, mrow, rowsum);
    gemm_softmax_kernel<<<8 * NCH_PAD, 256, 0, stream>>>(ib, fb, mrow, rowsum);
    final_kernel<<<1, 1024, 0, stream>>>(rowsum, tlogit, mrow, out);
}

// Round 7
// 302.249 us; speedup vs baseline: 1.1001x; 1.1001x over previous
//
#include <hip/hip_runtime.h>
#include <hip/hip_bf16.h>

#define TEMP_INV 20.0f
#define BATCH    1024
#define NSAMP    100000
#define NFEAT    256
#define BM       128
#define BN       128
#define BK       64
#define NCH      ((NSAMP + BN - 1) / BN)   /* 782 */
#define NCH_PAD  784                        /* 8 * 98 */

typedef __bf16 bf16x8 __attribute__((ext_vector_type(8)));
typedef float  f32x4  __attribute__((ext_vector_type(4)));
typedef float  f32x4v __attribute__((ext_vector_type(4)));

// async global->LDS, 16B per lane; LDS dest = wave-uniform base + lane*16
#define GLOAD_LDS16(g, l) __builtin_amdgcn_global_load_lds(               \
    (const __attribute__((address_space(1))) void*)(g),                   \
    (__attribute__((address_space(3))) void*)(l), 16, 0, 0)

// ---------------------------------------------------------------------------
// Kernel 1 (fused): bf16 convert of feats (+zero pad) and inputs (NT loads/
// stores), out zero-init, and per-row target logit + softmax shift.
//   [0,3125)     feats convert  (4x8 elems/thread)
//   [3125,3128)  zero-pad fb rows 100000..100096; b==3125,t0 zeroes out[0]
//   [3128,3160)  inputs convert
//   [3160,3416)  target: row = (b-3160)*4 + wave; tlogit + mrow
// mrow = 5.4*||x_row|| (Gumbel-mode shift; exponents stay f32-safe, padded
// zero-rows underflow to 0 -> no masking needed anywhere).
// ---------------------------------------------------------------------------
__global__ __launch_bounds__(256) void convert_target_kernel(
    const float* __restrict__ feats, const float* __restrict__ inputs,
    const int* __restrict__ targets,
    __bf16* __restrict__ fb, __bf16* __restrict__ ib,
    float* __restrict__ tlogit, float* __restrict__ mrow,
    float* __restrict__ out)
{
    int b = blockIdx.x;
    if (b < 3125) {
        size_t u0 = (size_t)b * 1024 + threadIdx.x;
        #pragma unroll
        for (int i = 0; i < 4; i++) {
            size_t u = u0 + (size_t)i * 256;
            const f32x4v* src = (const f32x4v*)(feats + u * 8);
            f32x4v a = __builtin_nontemporal_load(src);
            f32x4v c = __builtin_nontemporal_load(src + 1);
            bf16x8 o;
            o[0] = (__bf16)a[0]; o[1] = (__bf16)a[1]; o[2] = (__bf16)a[2]; o[3] = (__bf16)a[3];
            o[4] = (__bf16)c[0]; o[5] = (__bf16)c[1]; o[6] = (__bf16)c[2]; o[7] = (__bf16)c[3];
            __builtin_nontemporal_store(o, (bf16x8*)(fb + u * 8));
        }
    } else if (b < 3128) {
        size_t u0 = 3200000 + (size_t)(b - 3125) * 1024 + threadIdx.x;
        bf16x8 z;
        #pragma unroll
        for (int q = 0; q < 8; q++) z[q] = (__bf16)0.0f;
        #pragma unroll
        for (int i = 0; i < 4; i++)
            *(bf16x8*)(fb + (u0 + (size_t)i * 256) * 8) = z;
        if (b == 3125 && threadIdx.x == 0) out[0] = 0.0f;
    } else if (b < 3160) {
        size_t u0 = (size_t)(b - 3128) * 1024 + threadIdx.x;
        #pragma unroll
        for (int i = 0; i < 4; i++) {
            size_t u = u0 + (size_t)i * 256;
            const f32x4v* src = (const f32x4v*)(inputs + u * 8);
            f32x4v a = __builtin_nontemporal_load(src);
            f32x4v c = __builtin_nontemporal_load(src + 1);
            bf16x8 o;
            o[0] = (__bf16)a[0]; o[1] = (__bf16)a[1]; o[2] = (__bf16)a[2]; o[3] = (__bf16)a[3];
            o[4] = (__bf16)c[0]; o[5] = (__bf16)c[1]; o[6] = (__bf16)c[2]; o[7] = (__bf16)c[3];
            __builtin_nontemporal_store(o, (bf16x8*)(ib + u * 8));
        }
    } else {
        int lane = threadIdx.x & 63;
        int wid  = threadIdx.x >> 6;
        int row  = (b - 3160) * 4 + wid;
        int tgt  = targets[row];
        const float4* a = (const float4*)(inputs + (size_t)row * NFEAT);
        const float4* f = (const float4*)(feats  + (size_t)tgt * NFEAT);
        float4 av = a[lane];
        float4 fv = f[lane];
        float d  = av.x * fv.x + av.y * fv.y + av.z * fv.z + av.w * fv.w;
        float n2 = av.x * av.x + av.y * av.y + av.z * av.z + av.w * av.w;
        #pragma unroll
        for (int off = 1; off < 64; off <<= 1) {
            d  += __shfl_xor(d, off, 64);
            n2 += __shfl_xor(n2, off, 64);
        }
        if (lane == 0) {
            tlogit[row] = d * TEMP_INV;
            mrow[row]   = 5.4f * sqrtf(n2);
        }
    }
}

// ---------------------------------------------------------------------------
// Kernel 2: bf16 MFMA GEMM. B staged via global_load_lds (XOR-swizzled,
// B-ONLY in LDS: 16 KB slab); A-fragments loaded DIRECTLY from global
// (L1/L2-resident 512 KB, 16 rows x 64B coalesced per instr; loads pipeline
// across the barrier and interleave with MFMA). Fixed-shift exp-sum epilogue
// into per-chunk partials (no atomics). 128x128 tile, 4 waves (2x2 of 64x64).
// ---------------------------------------------------------------------------
__global__ __launch_bounds__(256, 4) void gemm_softmax_kernel(
    const __bf16* __restrict__ A, const __bf16* __restrict__ B,
    const float* __restrict__ mrow, float* __restrict__ partials)
{
    int L  = blockIdx.x;
    int j  = L & 7;                 // XCD id (round-robin)
    int t  = L >> 3;
    int mx = t & 7;                 // m-tile sweeps fastest -> B-chunk L2 reuse
    int ny = (t >> 3) * 8 + j;
    if (ny >= NCH) return;
    int m0 = mx * BM;
    int n0 = ny * BN;

    __shared__ __bf16 Blds[BN][BK];   // 16 KB
    __shared__ float  red[2][BM];

    int tid  = threadIdx.x;
    int lane = tid & 63;
    int wid  = tid >> 6;
    int wm   = wid & 1;
    int wn   = wid >> 1;
    int lrow = lane & 15;
    int quad = lane >> 4;

    f32x4 acc[4][4] = {};

    // B staging addresses: wave wid covers slab rows wid*32..+32 (4 instrs)
    int rowoff = lane >> 3;
    int p      = lane & 7;
    int kc     = p ^ rowoff;        // XOR chunk swizzle (0 bank conflicts)
    const __bf16* Bg = B + (size_t)(n0 + wid * 32 + rowoff) * NFEAT + kc * 8;
    // A fragment base: rows m0 + wm*64 + mi*16 + lrow, k = k0 + ks*32 + quad*8
    const __bf16* Ab = A + (size_t)(m0 + wm * 64 + lrow) * NFEAT + quad * 8;

    for (int k0 = 0; k0 < NFEAT; k0 += BK) {
        __syncthreads();
        #pragma unroll
        for (int i = 0; i < 4; i++)
            GLOAD_LDS16(Bg + k0 + i * 8 * NFEAT, &Blds[wid * 32 + i * 8][0]);
        __syncthreads();
        #pragma unroll
        for (int ks = 0; ks < 2; ks++) {
            bf16x8 af[4], bfr[4];
            #pragma unroll
            for (int mi = 0; mi < 4; mi++)
                af[mi] = *(const bf16x8*)(Ab + (size_t)mi * 16 * NFEAT + k0 + ks * 32);
            #pragma unroll
            for (int ni = 0; ni < 4; ni++) {
                int R = wn * 64 + ni * 16 + lrow;
                bfr[ni] = *(bf16x8*)&Blds[R][((ks * 4 + quad) ^ (R & 7)) * 8];
            }
            #pragma unroll
            for (int mi = 0; mi < 4; mi++)
                #pragma unroll
                for (int ni = 0; ni < 4; ni++)
                    acc[mi][ni] = __builtin_amdgcn_mfma_f32_16x16x32_bf16(
                        af[mi], bfr[ni], acc[mi][ni], 0, 0, 0);
        }
    }

    // ---- epilogue: s = sum_cols exp(20*acc - m_row), plain add reduce ----
    // C layout: row = quad*4 + reg, col = lane&15 per 16x16 tile
    #pragma unroll
    for (int mi = 0; mi < 4; mi++) {
        #pragma unroll
        for (int reg = 0; reg < 4; reg++) {
            float mrv = mrow[m0 + wm * 64 + mi * 16 + quad * 4 + reg];
            float s = __expf(acc[mi][0][reg] * TEMP_INV - mrv)
                    + __expf(acc[mi][1][reg] * TEMP_INV - mrv)
                    + __expf(acc[mi][2][reg] * TEMP_INV - mrv)
                    + __expf(acc[mi][3][reg] * TEMP_INV - mrv);
            #pragma unroll
            for (int off = 1; off < 16; off <<= 1)
                s += __shfl_xor(s, off, 64);
            if (lrow == 0)
                red[wn][wm * 64 + mi * 16 + quad * 4 + reg] = s;
        }
    }
    __syncthreads();
    if (tid < BM)
        partials[(size_t)ny * BATCH + (m0 + tid)] = red[0][tid] + red[1][tid];
}

// ---------------------------------------------------------------------------
// Kernel 3: sum partials -> lse = m_row + log(S) -> nll -> mean (atomicAdd,
// one per block, 32 blocks, out zeroed by convert kernel).
// ---------------------------------------------------------------------------
__global__ __launch_bounds__(256) void reduce_kernel(
    const float* __restrict__ partials, const float* __restrict__ tlogit,
    const float* __restrict__ mrow, float* __restrict__ out)
{
    __shared__ float red2[8][32];
    int tid = threadIdx.x;
    int rl  = tid & 31;
    int sp  = tid >> 5;
    int row = blockIdx.x * 32 + rl;
    int cs  = sp * 98;
    int ce  = cs + 98 < NCH ? cs + 98 : NCH;
    float s = 0.f;
    #pragma unroll 4
    for (int c = cs; c < ce; c++)
        s += partials[(size_t)c * BATCH + row];
    red2[sp][rl] = s;
    __syncthreads();
    if (tid < 32) {
        float S = 0.f;
        #pragma unroll
        for (int q = 0; q < 8; q++) S += red2[q][rl];
        float nll = (mrow[row] + logf(S)) - tlogit[row];
        #pragma unroll
        for (int off = 1; off < 32; off <<= 1)
            nll += __shfl_xor(nll, off, 64);
        if (rl == 0) atomicAdd(out, nll * (1.0f / BATCH));
    }
}

// ---------------------------------------------------------------------------
extern "C" void kernel_launch(void* const* d_in, const int* in_sizes, int n_in,
                              void* d_out, int out_size, void* d_ws, size_t ws_size,
                              hipStream_t stream) {
    const float* inputs  = (const float*)d_in[0];
    const int*   targets = (const int*)d_in[1];
    const float* feats   = (const float*)d_in[2];
    float* out = (float*)d_out;

    // ws layout (bytes):
    //   fb       : 0          .. 51,249,152   (100096*256 bf16)
    //   ib       : 51,249,152 .. 51,773,440   (1024*256 bf16)
    //   partials : 51,773,440 .. 54,976,512   (782*1024 f32)
    //   tlogit   : 54,976,512 .. +4096
    //   mrow     : 54,980,608 .. +4096
    __bf16* fb       = (__bf16*)d_ws;
    __bf16* ib       = (__bf16*)((char*)d_ws + 51249152);
    float*  partials = (float*)((char*)d_ws + 51773440);
    float*  tlogit   = (float*)((char*)d_ws + 54976512);
    float*  mrow     = (float*)((char*)d_ws + 54980608);

    convert_target_kernel<<<3416, 256, 0, stream>>>(
        feats, inputs, targets, fb, ib, tlogit, mrow, out);
    gemm_softmax_kernel<<<8 * NCH_PAD, 256, 0, stream>>>(ib, fb, mrow, partials);
    reduce_kernel<<<BATCH / 32, 256, 0, stream>>>(partials, tlogit, mrow, out);
}

// Round 8
// 280.675 us; speedup vs baseline: 1.1847x; 1.0769x over previous
//
#include <hip/hip_runtime.h>
#include <hip/hip_bf16.h>

#define TEMP_INV 20.0f
#define BATCH    1024
#define NSAMP    100000
#define NFEAT    256
#define BM       128
#define BN       128
#define BK       64
#define NCH      ((NSAMP + BN - 1) / BN)   /* 782 */
#define NCH_PAD  784                        /* 8 * 98 */

typedef __bf16 bf16x8 __attribute__((ext_vector_type(8)));
typedef float  f32x4  __attribute__((ext_vector_type(4)));

// async global->LDS, 16B per lane; LDS dest = wave-uniform base + lane*16
#define GLOAD_LDS16(g, l) __builtin_amdgcn_global_load_lds(               \
    (const __attribute__((address_space(1))) void*)(g),                   \
    (__attribute__((address_space(3))) void*)(l), 16, 0, 0)

// ---------------------------------------------------------------------------
// Kernel 1 (aux): inputs fp32->bf16 (0.5 MB), per-row target logit + softmax
// shift mrow = 5.4*||x_row||, and out zero-init.
//   blocks [0,32)    : inputs convert (4 x 8 elems per thread)
//   blocks [32,288)  : target row = (b-32)*4 + wave
// ---------------------------------------------------------------------------
__global__ __launch_bounds__(256) void aux_kernel(
    const float* __restrict__ feats, const float* __restrict__ inputs,
    const int* __restrict__ targets, __bf16* __restrict__ ib,
    float* __restrict__ tlogit, float* __restrict__ mrow,
    float* __restrict__ out)
{
    int b = blockIdx.x;
    if (b < 32) {
        if (b == 0 && threadIdx.x == 0) out[0] = 0.0f;
        size_t u0 = (size_t)b * 1024 + threadIdx.x;
        #pragma unroll
        for (int i = 0; i < 4; i++) {
            size_t u = u0 + (size_t)i * 256;
            const float4* src = (const float4*)(inputs + u * 8);
            float4 a = src[0], c = src[1];
            bf16x8 o;
            o[0] = (__bf16)a.x; o[1] = (__bf16)a.y; o[2] = (__bf16)a.z; o[3] = (__bf16)a.w;
            o[4] = (__bf16)c.x; o[5] = (__bf16)c.y; o[6] = (__bf16)c.z; o[7] = (__bf16)c.w;
            *(bf16x8*)(ib + u * 8) = o;
        }
    } else {
        int lane = threadIdx.x & 63;
        int wid  = threadIdx.x >> 6;
        int row  = (b - 32) * 4 + wid;
        int tgt  = targets[row];
        const float4* a = (const float4*)(inputs + (size_t)row * NFEAT);
        const float4* f = (const float4*)(feats  + (size_t)tgt * NFEAT);
        float4 av = a[lane];
        float4 fv = f[lane];
        float d  = av.x * fv.x + av.y * fv.y + av.z * fv.z + av.w * fv.w;
        float n2 = av.x * av.x + av.y * av.y + av.z * av.z + av.w * av.w;
        #pragma unroll
        for (int off = 1; off < 64; off <<= 1) {
            d  += __shfl_xor(d, off, 64);
            n2 += __shfl_xor(n2, off, 64);
        }
        if (lane == 0) {
            tlogit[row] = d * TEMP_INV;
            mrow[row]   = 5.4f * sqrtf(n2);
        }
    }
}

// ---------------------------------------------------------------------------
// Kernel 2: bf16 MFMA GEMM with INLINE fp32->bf16 B staging (feats never
// pre-converted). A staged via global_load_lds from bf16 ib (proven R5 path).
// B: per lane float4x2 load -> cvt -> ds_write_b128 into the SAME XOR-swizzled
// layout global_load_lds produced (writes lane-contiguous => conflict-free;
// read side identical to R5). Zero rows >= NSAMP handled at stage time.
// 128x128 tile, BK=64, 4 waves (2x2 of 64x64). Fixed-shift exp-sum epilogue.
// ---------------------------------------------------------------------------
__global__ __launch_bounds__(256, 4) void gemm_softmax_kernel(
    const __bf16* __restrict__ A, const float* __restrict__ F,
    const float* __restrict__ mrow, float* __restrict__ partials)
{
    int L  = blockIdx.x;
    int j  = L & 7;                 // XCD id (round-robin)
    int t  = L >> 3;
    int mx = t & 7;                 // m-tile sweeps fastest -> B-tile L2 reuse
    int ny = (t >> 3) * 8 + j;
    if (ny >= NCH) return;
    int m0 = mx * BM;
    int n0 = ny * BN;

    __shared__ __bf16 Alds[BM][BK];   // 16 KB
    __shared__ __bf16 Blds[BN][BK];   // 16 KB
    __shared__ float  red[2][BM];

    int tid  = threadIdx.x;
    int lane = tid & 63;
    int wid  = tid >> 6;
    int wm   = wid & 1;
    int wn   = wid >> 1;
    int lrow = lane & 15;
    int quad = lane >> 4;

    f32x4 acc[4][4] = {};

    // shared staging lane decomposition (R5 address math)
    int rowoff = lane >> 3;          // 0..7
    int p      = lane & 7;           // chunk position within row
    int kc     = p ^ rowoff;         // global 16B chunk for swizzled pos p
    const __bf16* Ag = A + (size_t)(m0 + wid * 32 + rowoff) * NFEAT + kc * 8;
    // B global base: row = n0 + wid*32 + i*8 + rowoff, k = k0 + kc*8 (fp32)
    const float* Fg = F + (size_t)(n0 + wid * 32 + rowoff) * NFEAT + kc * 8;
    int growb = n0 + wid * 32 + rowoff;
    // LDS dest for B: contiguous chunks, lane-order (matches gload semantics)
    __bf16* Bdst = &Blds[wid * 32][0] + lane * 8;

    for (int k0 = 0; k0 < NFEAT; k0 += BK) {
        __syncthreads();
        #pragma unroll
        for (int i = 0; i < 4; i++)
            GLOAD_LDS16(Ag + k0 + i * 8 * NFEAT, &Alds[wid * 32 + i * 8][0]);
        #pragma unroll
        for (int i = 0; i < 4; i++) {
            const float* gp = Fg + k0 + (size_t)i * 8 * NFEAT;
            bf16x8 o;
            if (growb + i * 8 < NSAMP) {
                float4 f0 = *(const float4*)gp;
                float4 f1 = *(const float4*)(gp + 4);
                o[0] = (__bf16)f0.x; o[1] = (__bf16)f0.y;
                o[2] = (__bf16)f0.z; o[3] = (__bf16)f0.w;
                o[4] = (__bf16)f1.x; o[5] = (__bf16)f1.y;
                o[6] = (__bf16)f1.z; o[7] = (__bf16)f1.w;
            } else {
                #pragma unroll
                for (int q = 0; q < 8; q++) o[q] = (__bf16)0.0f;
            }
            *(bf16x8*)(Bdst + i * 512) = o;   // 64 chunks * 8 elems per step
        }
        __syncthreads();
        #pragma unroll
        for (int ks = 0; ks < 2; ks++) {
            bf16x8 af[4], bfr[4];
            #pragma unroll
            for (int mi = 0; mi < 4; mi++) {
                int R = wm * 64 + mi * 16 + lrow;
                af[mi] = *(bf16x8*)&Alds[R][((ks * 4 + quad) ^ (R & 7)) * 8];
            }
            #pragma unroll
            for (int ni = 0; ni < 4; ni++) {
                int R = wn * 64 + ni * 16 + lrow;
                bfr[ni] = *(bf16x8*)&Blds[R][((ks * 4 + quad) ^ (R & 7)) * 8];
            }
            #pragma unroll
            for (int mi = 0; mi < 4; mi++)
                #pragma unroll
                for (int ni = 0; ni < 4; ni++)
                    acc[mi][ni] = __builtin_amdgcn_mfma_f32_16x16x32_bf16(
                        af[mi], bfr[ni], acc[mi][ni], 0, 0, 0);
        }
    }

    // ---- epilogue: s = sum_cols exp(20*acc - m_row), plain add reduce ----
    // C layout: row = quad*4 + reg, col = lane&15 per 16x16 tile
    #pragma unroll
    for (int mi = 0; mi < 4; mi++) {
        #pragma unroll
        for (int reg = 0; reg < 4; reg++) {
            float mrv = mrow[m0 + wm * 64 + mi * 16 + quad * 4 + reg];
            float s = __expf(acc[mi][0][reg] * TEMP_INV - mrv)
                    + __expf(acc[mi][1][reg] * TEMP_INV - mrv)
                    + __expf(acc[mi][2][reg] * TEMP_INV - mrv)
                    + __expf(acc[mi][3][reg] * TEMP_INV - mrv);
            #pragma unroll
            for (int off = 1; off < 16; off <<= 1)
                s += __shfl_xor(s, off, 64);
            if (lrow == 0)
                red[wn][wm * 64 + mi * 16 + quad * 4 + reg] = s;
        }
    }
    __syncthreads();
    if (tid < BM)
        partials[(size_t)ny * BATCH + (m0 + tid)] = red[0][tid] + red[1][tid];
}

// ---------------------------------------------------------------------------
// Kernel 3: sum partials -> lse = m_row + log(S) -> nll -> mean (atomicAdd,
// one per block, 32 blocks; out zeroed by aux kernel).
// ---------------------------------------------------------------------------
__global__ __launch_bounds__(256) void reduce_kernel(
    const float* __restrict__ partials, const float* __restrict__ tlogit,
    const float* __restrict__ mrow, float* __restrict__ out)
{
    __shared__ float red2[8][32];
    int tid = threadIdx.x;
    int rl  = tid & 31;
    int sp  = tid >> 5;
    int row = blockIdx.x * 32 + rl;
    int cs  = sp * 98;
    int ce  = cs + 98 < NCH ? cs + 98 : NCH;
    float s = 0.f;
    #pragma unroll 4
    for (int c = cs; c < ce; c++)
        s += partials[(size_t)c * BATCH + row];
    red2[sp][rl] = s;
    __syncthreads();
    if (tid < 32) {
        float S = 0.f;
        #pragma unroll
        for (int q = 0; q < 8; q++) S += red2[q][rl];
        float nll = (mrow[row] + logf(S)) - tlogit[row];
        #pragma unroll
        for (int off = 1; off < 32; off <<= 1)
            nll += __shfl_xor(nll, off, 64);
        if (rl == 0) atomicAdd(out, nll * (1.0f / BATCH));
    }
}

// ---------------------------------------------------------------------------
extern "C" void kernel_launch(void* const* d_in, const int* in_sizes, int n_in,
                              void* d_out, int out_size, void* d_ws, size_t ws_size,
                              hipStream_t stream) {
    const float* inputs  = (const float*)d_in[0];
    const int*   targets = (const int*)d_in[1];
    const float* feats   = (const float*)d_in[2];
    float* out = (float*)d_out;

    // ws layout (bytes):
    //   ib       : 0         .. 524,288     (1024*256 bf16)
    //   partials : 524,288   .. 3,727,360   (782*1024 f32)
    //   tlogit   : 3,727,360 .. +4096
    //   mrow     : 3,731,456 .. +4096
    __bf16* ib       = (__bf16*)d_ws;
    float*  partials = (float*)((char*)d_ws + 524288);
    float*  tlogit   = (float*)((char*)d_ws + 3727360);
    float*  mrow     = (float*)((char*)d_ws + 3731456);

    aux_kernel<<<288, 256, 0, stream>>>(feats, inputs, targets, ib, tlogit, mrow, out);
    gemm_softmax_kernel<<<8 * NCH_PAD, 256, 0, stream>>>(ib, feats, mrow, partials);
    reduce_kernel<<<BATCH / 32, 256, 0, stream>>>(partials, tlogit, mrow, out);
}